// Round 8
// baseline (302.970 us; speedup 1.0000x reference)
//
#include <hip/hip_runtime.h>

#define D_   256
#define HW_  1024
#define N_   32768
#define K_   1024

#define MAXREF  8192
#define QMARGIN 5.0e-5f   // flag margin, s-units (need >= 3.05e-5 + 2*eps_screen)
#define RMARGIN 4.0e-5f   // refine qualification vs vref, s-units

typedef __attribute__((ext_vector_type(8))) short short8v;  // 8 bf16 (4 VGPRs)
typedef __attribute__((ext_vector_type(4))) float f32x4;    // MFMA acc

// ws layout (bytes) — unchanged from R7:
//   0       counter (int)
//   1024    list[MAXREF] ints
//   33792   B32[1024] floats
//   37888   A32[32768] floats
//   168960  cbAhi fragments (512 KB)
//   693248  cbAlo fragments (512 KB)
//
// zq-region scratch (floats; all consumed before gather overwrites):
//   [0, 262144)        top2 float4[2][32768]  (v1, k1, v2, pad)
//   [262144, 294912)   vref float[32768]
//   [294912, 360448)   cell u64[32768] (packed (d32bits<<32)|k, atomicMin)

// ---------------------------------------------------------------------------
__device__ __forceinline__ unsigned short f2bf_rne(float f) {
    unsigned u = __float_as_uint(f);
    unsigned r = u + 0x7FFFu + ((u >> 16) & 1u);
    return (unsigned short)(r >> 16);
}
__device__ __forceinline__ float bf2f(unsigned short h) {
    return __uint_as_float(((unsigned)h) << 16);
}

// numpy pairwise fp32 sum of squares over 256 elements (stride in elems).
__device__ __forceinline__ float np_sumsq_256(const float* a, int stride) {
    float blk[2];
    #pragma unroll
    for (int h = 0; h < 2; ++h) {
        const float* p = a + (size_t)h * 128 * stride;
        float r[8];
        #pragma unroll
        for (int j = 0; j < 8; ++j) {
            float v = p[(size_t)j * stride];
            r[j] = __fmul_rn(v, v);
        }
        for (int i = 1; i < 16; ++i) {
            #pragma unroll
            for (int j = 0; j < 8; ++j) {
                float v = p[(size_t)(i * 8 + j) * stride];
                r[j] = __fadd_rn(r[j], __fmul_rn(v, v));
            }
        }
        blk[h] = __fadd_rn(__fadd_rn(__fadd_rn(r[0], r[1]), __fadd_rn(r[2], r[3])),
                           __fadd_rn(__fadd_rn(r[4], r[5]), __fadd_rn(r[6], r[7])));
    }
    return __fadd_rn(blk[0], blk[1]);
}

// ---------------------------------------------------------------------------
// Fused prep: bnorm (blocks 0-3) | anorm (4-131) | cbsplit (132-259) | init (260)
// ---------------------------------------------------------------------------
__global__ __launch_bounds__(256) void prep_kernel(const float* __restrict__ z,
                                                   const float* __restrict__ cb,
                                                   float* __restrict__ A32,
                                                   float* __restrict__ B32,
                                                   short* __restrict__ cbAhi,
                                                   short* __restrict__ cbAlo,
                                                   int* __restrict__ counter) {
    const int blk = blockIdx.x;
    const int tid = threadIdx.x;
    if (blk < 4) {
        int k = blk * 256 + tid;
        B32[k] = np_sumsq_256(cb + (size_t)k * D_, 1);
    } else if (blk < 132) {
        int n  = (blk - 4) * 256 + tid;
        int b  = n >> 10;
        int hw = n & 1023;
        A32[n] = np_sumsq_256(z + (size_t)b * (D_ * HW_) + hw, HW_);
    } else if (blk < 260) {
        // fragment-ordered bf16 hi/lo split of codebook
        int c  = (blk - 132) * 256 + tid;   // 0..32767
        int kf = c >> 9;
        int ds = (c >> 6) & 7;
        int q  = (c >> 4) & 3;
        int r  = c & 15;
        int k  = kf * 16 + r;
        int d0 = ds * 32 + q * 8;
        const float* src = cb + (size_t)k * D_ + d0;
        short8v vh, vl;
        #pragma unroll
        for (int j = 0; j < 8; ++j) {
            float f = src[j];
            unsigned short h = f2bf_rne(f);
            float hf = bf2f(h);
            unsigned short l = f2bf_rne(f - hf);
            vh[j] = (short)h;
            vl[j] = (short)l;
        }
        *reinterpret_cast<short8v*>(cbAhi + (size_t)c * 8) = vh;
        *reinterpret_cast<short8v*>(cbAlo + (size_t)c * 8) = vl;
    } else {
        if (tid == 0) *counter = 0;
    }
}

// ---------------------------------------------------------------------------
// MFMA screening, K-split: block (px-tile, khalf) covers 128 px x 512 codes.
// Per-pixel top-2 of its half -> top2[khalf*N_ + n]. Grid dim3(256, 2):
// 512 blocks = 2 blocks/CU = 2 waves/SIMD (latency hiding vs R7's 1).
// ---------------------------------------------------------------------------
__global__ __launch_bounds__(256) void vq_screen_mfma(
        const float* __restrict__ z,
        const short8v* __restrict__ cbAhi,
        const short8v* __restrict__ cbAlo,
        const float* __restrict__ B32,
        float4* __restrict__ top2)
{
    __shared__ float zt[128][33];
    __shared__ float halfB[K_];

    const int tid  = threadIdx.x;
    const int lane = tid & 63;
    const int wave = tid >> 6;
    const int q    = lane >> 4;
    const int r    = lane & 15;

    const int p0    = blockIdx.x * 128;
    const int khalf = blockIdx.y;          // 0 or 1: codes [khalf*512, khalf*512+512)
    const int b     = p0 >> 10;
    const int hw0   = p0 & 1023;
    const int wpx0  = wave * 32;

    #pragma unroll
    for (int i = 0; i < 4; ++i) halfB[i * 256 + tid] = 0.5f * B32[i * 256 + tid];

    // ---- register-resident z b-frags (bf16 hi/lo split) ----
    short8v bhf[2][8], blf[2][8];
    for (int ds = 0; ds < 8; ++ds) {
        __syncthreads();
        #pragma unroll
        for (int i = 0; i < 16; ++i) {
            int dd = (tid >> 7) + 2 * i;
            int d  = ds * 32 + dd;
            zt[tid & 127][dd] =
                z[(size_t)b * (D_ * HW_) + (size_t)d * HW_ + hw0 + (tid & 127)];
        }
        __syncthreads();
        #pragma unroll
        for (int nf = 0; nf < 2; ++nf) {
            int px = wpx0 + nf * 16 + r;
            short8v vh, vl;
            #pragma unroll
            for (int j = 0; j < 8; ++j) {
                float f = zt[px][q * 8 + j];
                unsigned short h = f2bf_rne(f);
                float hf = bf2f(h);
                unsigned short l = f2bf_rne(f - hf);
                vh[j] = (short)h;
                vl[j] = (short)l;
            }
            bhf[nf][ds] = vh;
            blf[nf][ds] = vl;
        }
    }
    __syncthreads();

    float v1[2] = {3.4e38f, 3.4e38f};
    float v2[2] = {3.4e38f, 3.4e38f};
    int   k1[2] = {0, 0};

    for (int chl = 0; chl < 16; ++chl) {
        int ch = khalf * 16 + chl;
        f32x4 acc00 = {0.f,0.f,0.f,0.f}, acc01 = {0.f,0.f,0.f,0.f};
        f32x4 acc10 = {0.f,0.f,0.f,0.f}, acc11 = {0.f,0.f,0.f,0.f};

        #pragma unroll
        for (int ds = 0; ds < 8; ++ds) {
            int base0 = ((ch * 2 + 0) * 8 + ds) * 64 + lane;
            int base1 = ((ch * 2 + 1) * 8 + ds) * 64 + lane;
            short8v a0h = cbAhi[base0], a0l = cbAlo[base0];
            short8v a1h = cbAhi[base1], a1l = cbAlo[base1];

            acc00 = __builtin_amdgcn_mfma_f32_16x16x32_bf16(a0h, bhf[0][ds], acc00, 0,0,0);
            acc01 = __builtin_amdgcn_mfma_f32_16x16x32_bf16(a0h, bhf[1][ds], acc01, 0,0,0);
            acc10 = __builtin_amdgcn_mfma_f32_16x16x32_bf16(a1h, bhf[0][ds], acc10, 0,0,0);
            acc11 = __builtin_amdgcn_mfma_f32_16x16x32_bf16(a1h, bhf[1][ds], acc11, 0,0,0);

            acc00 = __builtin_amdgcn_mfma_f32_16x16x32_bf16(a0l, bhf[0][ds], acc00, 0,0,0);
            acc01 = __builtin_amdgcn_mfma_f32_16x16x32_bf16(a0l, bhf[1][ds], acc01, 0,0,0);
            acc10 = __builtin_amdgcn_mfma_f32_16x16x32_bf16(a1l, bhf[0][ds], acc10, 0,0,0);
            acc11 = __builtin_amdgcn_mfma_f32_16x16x32_bf16(a1l, bhf[1][ds], acc11, 0,0,0);

            acc00 = __builtin_amdgcn_mfma_f32_16x16x32_bf16(a0h, blf[0][ds], acc00, 0,0,0);
            acc01 = __builtin_amdgcn_mfma_f32_16x16x32_bf16(a0h, blf[1][ds], acc01, 0,0,0);
            acc10 = __builtin_amdgcn_mfma_f32_16x16x32_bf16(a1h, blf[0][ds], acc10, 0,0,0);
            acc11 = __builtin_amdgcn_mfma_f32_16x16x32_bf16(a1h, blf[1][ds], acc11, 0,0,0);
        }

        #pragma unroll
        for (int kf = 0; kf < 2; ++kf) {
            int kbase = ch * 32 + kf * 16 + q * 4;
            #pragma unroll
            for (int reg = 0; reg < 4; ++reg) {
                float hb = halfB[kbase + reg];
                int   kk = kbase + reg;
                {
                    float s = hb - ((kf == 0) ? acc00[reg] : acc10[reg]);
                    bool lt = s < v1[0];
                    v2[0] = lt ? v1[0] : fminf(v2[0], s);
                    k1[0] = lt ? kk : k1[0];
                    v1[0] = lt ? s  : v1[0];
                }
                {
                    float s = hb - ((kf == 0) ? acc01[reg] : acc11[reg]);
                    bool lt = s < v1[1];
                    v2[1] = lt ? v1[1] : fminf(v2[1], s);
                    k1[1] = lt ? kk : k1[1];
                    v1[1] = lt ? s  : v1[1];
                }
            }
        }
        __builtin_amdgcn_s_barrier();
    }

    // merge the 4 q-groups per pixel
    #pragma unroll
    for (int nf = 0; nf < 2; ++nf) {
        float a1 = v1[nf], a2 = v2[nf];
        int   ak = k1[nf];
        #pragma unroll
        for (int off = 16; off <= 32; off <<= 1) {
            float o1 = __shfl_xor(a1, off, 64);
            float o2 = __shfl_xor(a2, off, 64);
            int   ok = __shfl_xor(ak, off, 64);
            if (o1 < a1 || (o1 == a1 && ok < ak)) {
                a2 = fminf(a1, o2); a1 = o1; ak = ok;
            } else {
                a2 = fminf(a2, o1);
            }
        }
        if (q == 0) {
            int n = p0 + wpx0 + nf * 16 + r;
            top2[(size_t)khalf * N_ + n] = make_float4(a1, (float)ak, a2, 0.f);
        }
    }
}

// ---------------------------------------------------------------------------
// Merge the two K-half top-2s; write oidx + vref; flag near-ties into list
// and arm their atomicMin cell.
// ---------------------------------------------------------------------------
__global__ __launch_bounds__(256) void merge_flag(const float4* __restrict__ top2,
                                                  float* __restrict__ oidx,
                                                  float* __restrict__ vref,
                                                  unsigned long long* __restrict__ cell,
                                                  int* __restrict__ counter,
                                                  int* __restrict__ list) {
    int n = blockIdx.x * 256 + threadIdx.x;
    float4 t0 = top2[n];
    float4 t1 = top2[(size_t)N_ + n];
    int k0i = (int)t0.y, k1i = (int)t1.y;
    float v1; int kk; float v2;
    if (t1.x < t0.x || (t1.x == t0.x && k1i < k0i)) {
        v1 = t1.x; kk = k1i; v2 = fminf(t1.z, t0.x);
    } else {
        v1 = t0.x; kk = k0i; v2 = fminf(t0.z, t1.x);
    }
    oidx[n] = (float)kk;
    vref[n] = v1;
    if (v2 - v1 < QMARGIN) {
        int slot = atomicAdd(counter, 1);
        if (slot < MAXREF) {
            list[slot] = n;
            cell[n] = 0xFFFFFFFFFFFFFFFFull;
        }
    }
}

// ---------------------------------------------------------------------------
// Refinement: 8 flagged pixels share one codebook sweep per block. For each
// (px,k) with fp32 s - vref[px] < RMARGIN: np-emulate
// d32 = fsub_rn(fadd_rn(A32,B32), 2*fp32(fp64 dot)), atomicMin packed (d32,k)
// -> lexicographic min = numpy first-occurrence argmin. Order-independent.
// ---------------------------------------------------------------------------
__global__ __launch_bounds__(256) void refine_np2(const float* __restrict__ z,
                                                  const float* __restrict__ cb,
                                                  const float* __restrict__ A32,
                                                  const float* __restrict__ B32,
                                                  const float* __restrict__ vref,
                                                  const int* __restrict__ counter,
                                                  const int* __restrict__ list,
                                                  unsigned long long* __restrict__ cell) {
    __shared__ float zs[8][260];
    __shared__ int   pid[8];
    __shared__ float pvref[8];

    const int tid = threadIdx.x;
    int cnt = *counter;
    if (cnt > MAXREF) cnt = MAXREF;
    int i0 = blockIdx.x * 8;
    if (i0 >= cnt) return;

    if (tid < 8) {
        int idx   = i0 + tid;
        int valid = idx < cnt;
        int n     = list[valid ? idx : i0];
        pid[tid]   = n;
        pvref[tid] = valid ? vref[n] : -1e30f;   // invalid slot: never qualifies
    }
    __syncthreads();

    {   // stage z rows (8 px x 256 d); 8 values per thread
        int px = tid >> 5;
        int dl = tid & 31;
        int n  = pid[px];
        int b  = n >> 10, hw = n & 1023;
        const float* zb = z + (size_t)b * (D_ * HW_) + hw;
        #pragma unroll
        for (int j = 0; j < 8; ++j) {
            int d = dl * 8 + j;
            zs[px][d] = zb[(size_t)d * HW_];
        }
    }
    __syncthreads();

    #pragma unroll
    for (int jj = 0; jj < 4; ++jj) {
        int k = tid * 4 + jj;
        const float4* crow = reinterpret_cast<const float4*>(cb + (size_t)k * D_);
        float a[8] = {0.f,0.f,0.f,0.f,0.f,0.f,0.f,0.f};
        for (int d4 = 0; d4 < 64; ++d4) {
            float4 c4 = crow[d4];
            #pragma unroll
            for (int px = 0; px < 8; ++px) {
                a[px] = fmaf(c4.x, zs[px][d4 * 4 + 0], a[px]);
                a[px] = fmaf(c4.y, zs[px][d4 * 4 + 1], a[px]);
                a[px] = fmaf(c4.z, zs[px][d4 * 4 + 2], a[px]);
                a[px] = fmaf(c4.w, zs[px][d4 * 4 + 3], a[px]);
            }
        }
        float hb = 0.5f * B32[k];
        #pragma unroll
        for (int px = 0; px < 8; ++px) {
            float s = hb - a[px];
            if (s - pvref[px] < RMARGIN) {
                int n = pid[px];
                double a0 = 0.0, a1 = 0.0, a2 = 0.0, a3 = 0.0;
                for (int d4 = 0; d4 < 64; ++d4) {
                    float4 c4 = crow[d4];
                    a0 = fma((double)c4.x, (double)zs[px][d4 * 4 + 0], a0);
                    a1 = fma((double)c4.y, (double)zs[px][d4 * 4 + 1], a1);
                    a2 = fma((double)c4.z, (double)zs[px][d4 * 4 + 2], a2);
                    a3 = fma((double)c4.w, (double)zs[px][d4 * 4 + 3], a3);
                }
                float C32 = (float)((a0 + a1) + (a2 + a3));
                float d32 = __fsub_rn(__fadd_rn(A32[n], B32[k]), __fadd_rn(C32, C32));
                unsigned long long key =
                    ((unsigned long long)__float_as_uint(d32) << 32) | (unsigned)k;
                atomicMin(&cell[n], key);
            }
        }
    }
}

// ---------------------------------------------------------------------------
__global__ __launch_bounds__(256) void finalize_kernel(const int* __restrict__ counter,
                                                       const int* __restrict__ list,
                                                       const unsigned long long* __restrict__ cell,
                                                       float* __restrict__ oidx) {
    int cnt = *counter;
    if (cnt > MAXREF) cnt = MAXREF;
    for (int i = blockIdx.x * 256 + threadIdx.x; i < cnt; i += gridDim.x * 256) {
        int n = list[i];
        oidx[n] = (float)(unsigned)(cell[n] & 0xFFFFFFFFull);
    }
}

// ---------------------------------------------------------------------------
__global__ __launch_bounds__(256) void gather_kernel(const float* __restrict__ cb,
                                                     const float* __restrict__ oidx,
                                                     float* __restrict__ zq) {
    const int tid  = threadIdx.x;
    const int s_nl = tid & 63;
    const int s_dw = tid >> 6;
    const int p0   = blockIdx.x * 64;
    const int b    = p0 >> 10;
    const int hw0  = p0 & 1023;

    int idxn = (int)oidx[p0 + s_nl];
    const float4* crow = reinterpret_cast<const float4*>(cb + (size_t)idxn * D_);
    float* zqb = zq + (size_t)b * (D_ * HW_) + hw0;
    #pragma unroll
    for (int r = 0; r < 16; ++r) {
        int d4 = s_dw * 16 + r;
        float4 c4 = crow[d4];
        int d = d4 * 4;
        zqb[(size_t)(d + 0) * HW_ + s_nl] = c4.x;
        zqb[(size_t)(d + 1) * HW_ + s_nl] = c4.y;
        zqb[(size_t)(d + 2) * HW_ + s_nl] = c4.z;
        zqb[(size_t)(d + 3) * HW_ + s_nl] = c4.w;
    }
}

extern "C" void kernel_launch(void* const* d_in, const int* in_sizes, int n_in,
                              void* d_out, int out_size, void* d_ws, size_t ws_size,
                              hipStream_t stream) {
    const float* z  = (const float*)d_in[0];   // [32,256,32,32] fp32
    const float* cb = (const float*)d_in[1];   // [1024,256] fp32

    float* zq   = (float*)d_out;
    float* oidx = zq + (size_t)N_ * D_;

    char* ws = (char*)d_ws;
    int*    counter = (int*)(ws + 0);
    int*    list    = (int*)(ws + 1024);
    float*  B32     = (float*)(ws + 33792);
    float*  A32     = (float*)(ws + 37888);
    short*  cbAhi   = (short*)(ws + 168960);
    short*  cbAlo   = (short*)(ws + 693248);

    // zq-region scratch (consumed before gather overwrites)
    float4*             top2 = (float4*)zq;                         // 2*N_ float4
    float*              vref = zq + 262144;                         // N_ floats
    unsigned long long* cell = (unsigned long long*)(zq + 294912);  // N_ u64

    prep_kernel<<<261, 256, 0, stream>>>(z, cb, A32, B32, cbAhi, cbAlo, counter);
    vq_screen_mfma<<<dim3(N_ / 128, 2), 256, 0, stream>>>(
        z, (const short8v*)cbAhi, (const short8v*)cbAlo, B32, top2);
    merge_flag<<<N_ / 256, 256, 0, stream>>>(top2, oidx, vref, cell, counter, list);
    refine_np2<<<MAXREF / 8, 256, 0, stream>>>(z, cb, A32, B32, vref, counter, list, cell);
    finalize_kernel<<<32, 256, 0, stream>>>(counter, list, cell, oidx);
    gather_kernel<<<N_ / 64, 256, 0, stream>>>(cb, oidx, zq);
}

// Round 9
// 211.436 us; speedup vs baseline: 1.4329x; 1.4329x over previous
//
#include <hip/hip_runtime.h>

#define D_   256
#define HW_  1024
#define N_   32768
#define K_   1024

#define MAXREF  8192
#define QMARGIN 5.0e-5f   // flag margin, s-units (needs >= 3.05e-5 + 2*eps_screen ~ 3.75e-5)
#define RMARGIN 4.0e-5f   // refine qualification vs vref, s-units

typedef __attribute__((ext_vector_type(8))) short short8v;  // 8 bf16 (4 VGPRs)
typedef __attribute__((ext_vector_type(4))) float f32x4;    // MFMA acc

// ws layout (bytes):
//   0       counter (int)
//   1024    list[MAXREF] ints
//   33792   B32[1024] floats
//   37888   A32[32768] floats
//   168960  cbAhi fragments (512 KB)
//   693248  cbAlo fragments (512 KB)
//
// zq-region scratch (consumed by refine/finalize before gather overwrites):
//   vref = zq[0 .. N)            (float)
//   cell = zq[N .. 3N)           (u64, packed (d32bits<<32)|k, atomicMin)

// ---------------------------------------------------------------------------
__device__ __forceinline__ unsigned short f2bf_rne(float f) {
    unsigned u = __float_as_uint(f);
    unsigned r = u + 0x7FFFu + ((u >> 16) & 1u);
    return (unsigned short)(r >> 16);
}
__device__ __forceinline__ float bf2f(unsigned short h) {
    return __uint_as_float(((unsigned)h) << 16);
}

// numpy pairwise fp32 sum of squares over 256 elements (stride in elems).
__device__ __forceinline__ float np_sumsq_256(const float* a, int stride) {
    float blk[2];
    #pragma unroll
    for (int h = 0; h < 2; ++h) {
        const float* p = a + (size_t)h * 128 * stride;
        float r[8];
        #pragma unroll
        for (int j = 0; j < 8; ++j) {
            float v = p[(size_t)j * stride];
            r[j] = __fmul_rn(v, v);
        }
        for (int i = 1; i < 16; ++i) {
            #pragma unroll
            for (int j = 0; j < 8; ++j) {
                float v = p[(size_t)(i * 8 + j) * stride];
                r[j] = __fadd_rn(r[j], __fmul_rn(v, v));
            }
        }
        blk[h] = __fadd_rn(__fadd_rn(__fadd_rn(r[0], r[1]), __fadd_rn(r[2], r[3])),
                           __fadd_rn(__fadd_rn(r[4], r[5]), __fadd_rn(r[6], r[7])));
    }
    return __fadd_rn(blk[0], blk[1]);
}

// ---------------------------------------------------------------------------
// Fused prep: bnorm (blocks 0-3) | anorm (4-131) | cbsplit (132-259) | init (260)
// ---------------------------------------------------------------------------
__global__ __launch_bounds__(256) void prep_kernel(const float* __restrict__ z,
                                                   const float* __restrict__ cb,
                                                   float* __restrict__ A32,
                                                   float* __restrict__ B32,
                                                   short* __restrict__ cbAhi,
                                                   short* __restrict__ cbAlo,
                                                   int* __restrict__ counter) {
    const int blk = blockIdx.x;
    const int tid = threadIdx.x;
    if (blk < 4) {
        int k = blk * 256 + tid;
        B32[k] = np_sumsq_256(cb + (size_t)k * D_, 1);
    } else if (blk < 132) {
        int n  = (blk - 4) * 256 + tid;
        int b  = n >> 10;
        int hw = n & 1023;
        A32[n] = np_sumsq_256(z + (size_t)b * (D_ * HW_) + hw, HW_);
    } else if (blk < 260) {
        // fragment-ordered bf16 hi/lo split of codebook
        int c  = (blk - 132) * 256 + tid;   // 0..32767
        int kf = c >> 9;
        int ds = (c >> 6) & 7;
        int q  = (c >> 4) & 3;
        int r  = c & 15;
        int k  = kf * 16 + r;
        int d0 = ds * 32 + q * 8;
        const float* src = cb + (size_t)k * D_ + d0;
        short8v vh, vl;
        #pragma unroll
        for (int j = 0; j < 8; ++j) {
            float f = src[j];
            unsigned short h = f2bf_rne(f);
            float hf = bf2f(h);
            unsigned short l = f2bf_rne(f - hf);
            vh[j] = (short)h;
            vl[j] = (short)l;
        }
        *reinterpret_cast<short8v*>(cbAhi + (size_t)c * 8) = vh;
        *reinterpret_cast<short8v*>(cbAlo + (size_t)c * 8) = vl;
    } else {
        if (tid == 0) *counter = 0;
    }
}

// ---------------------------------------------------------------------------
// MFMA screening v3: 512 threads (8 waves), 128 px/block, full K.
// Wave w owns px = w*16 + r (ONE b-frag set -> 64 frag VGPRs). Staging is
// shared across all 8 waves (done once per tile). Top-2 + flag fused here.
// ---------------------------------------------------------------------------
__global__ __launch_bounds__(512, 4) void vq_screen3(
        const float* __restrict__ z,
        const short8v* __restrict__ cbAhi,
        const short8v* __restrict__ cbAlo,
        const float* __restrict__ B32,
        float* __restrict__ oidx,
        float* __restrict__ vref,
        unsigned long long* __restrict__ cell,
        int* __restrict__ counter,
        int* __restrict__ list)
{
    __shared__ float zt[128][33];     // 16.9 KB; bank = (px+dd)%32 -> conflict-free
    __shared__ float halfB[K_];       // 4 KB

    const int tid  = threadIdx.x;
    const int lane = tid & 63;
    const int wave = tid >> 6;        // 0..7
    const int q    = lane >> 4;       // 0..3
    const int r    = lane & 15;

    const int p0  = blockIdx.x * 128;
    const int b   = p0 >> 10;
    const int hw0 = p0 & 1023;

    halfB[tid]       = 0.5f * B32[tid];
    halfB[512 + tid] = 0.5f * B32[512 + tid];

    // ---- shared staging: 8 ds-passes; all 512 threads load, each wave
    //      converts its own 16-px b-frags (bf16 hi/lo split) ----
    short8v bhf[8], blf[8];
    const int spx = tid & 127;
    const int sdq = tid >> 7;         // 0..3
    const int px  = wave * 16 + r;
    for (int ds = 0; ds < 8; ++ds) {
        __syncthreads();
        #pragma unroll
        for (int j = 0; j < 8; ++j) {
            int dd = sdq * 8 + j;
            int d  = ds * 32 + dd;
            zt[spx][dd] = z[(size_t)b * (D_ * HW_) + (size_t)d * HW_ + hw0 + spx];
        }
        __syncthreads();
        short8v vh, vl;
        #pragma unroll
        for (int j = 0; j < 8; ++j) {
            float f = zt[px][q * 8 + j];
            unsigned short h = f2bf_rne(f);
            float hf = bf2f(h);
            unsigned short l = f2bf_rne(f - hf);
            vh[j] = (short)h;
            vl[j] = (short)l;
        }
        bhf[ds] = vh;
        blf[ds] = vl;
    }
    __syncthreads();

    // ---- k-loop: 2 independent acc chains, a-frags L1-broadcast ----
    float v1 = 3.4e38f, v2v = 3.4e38f;
    int   k1 = 0;

    for (int ch = 0; ch < 32; ++ch) {
        f32x4 acc0 = {0.f,0.f,0.f,0.f};
        f32x4 acc1 = {0.f,0.f,0.f,0.f};

        #pragma unroll
        for (int ds = 0; ds < 8; ++ds) {
            int base0 = ((ch * 2 + 0) * 8 + ds) * 64 + lane;
            int base1 = ((ch * 2 + 1) * 8 + ds) * 64 + lane;
            short8v a0h = cbAhi[base0], a0l = cbAlo[base0];
            short8v a1h = cbAhi[base1], a1l = cbAlo[base1];

            acc0 = __builtin_amdgcn_mfma_f32_16x16x32_bf16(a0h, bhf[ds], acc0, 0,0,0);
            acc1 = __builtin_amdgcn_mfma_f32_16x16x32_bf16(a1h, bhf[ds], acc1, 0,0,0);
            acc0 = __builtin_amdgcn_mfma_f32_16x16x32_bf16(a0l, bhf[ds], acc0, 0,0,0);
            acc1 = __builtin_amdgcn_mfma_f32_16x16x32_bf16(a1l, bhf[ds], acc1, 0,0,0);
            acc0 = __builtin_amdgcn_mfma_f32_16x16x32_bf16(a0h, blf[ds], acc0, 0,0,0);
            acc1 = __builtin_amdgcn_mfma_f32_16x16x32_bf16(a1h, blf[ds], acc1, 0,0,0);
        }

        // extraction: D row = q*4+reg (code), col = r (pixel)
        #pragma unroll
        for (int kf = 0; kf < 2; ++kf) {
            int kbase = ch * 32 + kf * 16 + q * 4;
            #pragma unroll
            for (int reg = 0; reg < 4; ++reg) {
                float s = halfB[kbase + reg] - ((kf == 0) ? acc0[reg] : acc1[reg]);
                int  kk = kbase + reg;
                bool lt = s < v1;
                v2v = lt ? v1 : fminf(v2v, s);
                k1  = lt ? kk : k1;
                v1  = lt ? s  : v1;
            }
        }
        __builtin_amdgcn_s_barrier();   // keep waves chunk-aligned for L1 reuse
    }

    // ---- merge the 4 q-groups per pixel (lanes l, l^16, l^32, l^48) ----
    float a1 = v1, a2 = v2v;
    int   ak = k1;
    #pragma unroll
    for (int off = 16; off <= 32; off <<= 1) {
        float o1 = __shfl_xor(a1, off, 64);
        float o2 = __shfl_xor(a2, off, 64);
        int   ok = __shfl_xor(ak, off, 64);
        if (o1 < a1 || (o1 == a1 && ok < ak)) {
            a2 = fminf(a1, o2); a1 = o1; ak = ok;
        } else {
            a2 = fminf(a2, o1);
        }
    }
    if (q == 0) {
        int n = p0 + wave * 16 + r;
        oidx[n] = (float)ak;
        vref[n] = a1;
        if (a2 - a1 < QMARGIN) {
            int slot = atomicAdd(counter, 1);
            if (slot < MAXREF) {
                list[slot] = n;
                cell[n] = 0xFFFFFFFFFFFFFFFFull;
            }
        }
    }
}

// ---------------------------------------------------------------------------
// Refinement v3: 8 flagged px/block; loop-swapped so zs is read via float4
// once per (px,d4) and reused over the thread's 4 codes (a[4][8] accs).
// Qualifying (px,k): np-emulated d32 + atomicMin packed (d32,k).
// ---------------------------------------------------------------------------
__global__ __launch_bounds__(256) void refine_np3(const float* __restrict__ z,
                                                  const float* __restrict__ cb,
                                                  const float* __restrict__ A32,
                                                  const float* __restrict__ B32,
                                                  const float* __restrict__ vref,
                                                  const int* __restrict__ counter,
                                                  const int* __restrict__ list,
                                                  unsigned long long* __restrict__ cell) {
    __shared__ float zs[8][260];
    __shared__ int   pid[8];
    __shared__ float pvref[8];

    const int tid = threadIdx.x;
    int cnt = *counter;
    if (cnt > MAXREF) cnt = MAXREF;
    int i0 = blockIdx.x * 8;
    if (i0 >= cnt) return;

    if (tid < 8) {
        int idx   = i0 + tid;
        int valid = idx < cnt;
        int n     = list[valid ? idx : i0];
        pid[tid]   = n;
        pvref[tid] = valid ? vref[n] : -1e30f;   // invalid slot: never qualifies
    }
    __syncthreads();

    {   // stage z rows (8 px x 256 d)
        int px = tid >> 5;
        int dl = tid & 31;
        int n  = pid[px];
        int bb = n >> 10, hw = n & 1023;
        const float* zb = z + (size_t)bb * (D_ * HW_) + hw;
        #pragma unroll
        for (int j = 0; j < 8; ++j) {
            int d = dl * 8 + j;
            zs[px][d] = zb[(size_t)d * HW_];
        }
    }
    __syncthreads();

    const int kb = tid * 4;
    float a[4][8];
    #pragma unroll
    for (int jj = 0; jj < 4; ++jj)
        #pragma unroll
        for (int px = 0; px < 8; ++px) a[jj][px] = 0.f;

    for (int d4 = 0; d4 < 64; ++d4) {
        float4 c[4];
        #pragma unroll
        for (int jj = 0; jj < 4; ++jj)
            c[jj] = *reinterpret_cast<const float4*>(cb + (size_t)(kb + jj) * D_ + d4 * 4);
        #pragma unroll
        for (int px = 0; px < 8; ++px) {
            float4 z4 = *reinterpret_cast<const float4*>(&zs[px][d4 * 4]);
            #pragma unroll
            for (int jj = 0; jj < 4; ++jj) {
                a[jj][px] = fmaf(c[jj].x, z4.x, a[jj][px]);
                a[jj][px] = fmaf(c[jj].y, z4.y, a[jj][px]);
                a[jj][px] = fmaf(c[jj].z, z4.z, a[jj][px]);
                a[jj][px] = fmaf(c[jj].w, z4.w, a[jj][px]);
            }
        }
    }

    #pragma unroll
    for (int jj = 0; jj < 4; ++jj) {
        int k = kb + jj;
        float hb = 0.5f * B32[k];
        #pragma unroll
        for (int px = 0; px < 8; ++px) {
            float s = hb - a[jj][px];
            if (s - pvref[px] < RMARGIN) {
                int n = pid[px];
                const float4* crow = reinterpret_cast<const float4*>(cb + (size_t)k * D_);
                double a0 = 0.0, a1 = 0.0, a2 = 0.0, a3 = 0.0;
                for (int d4 = 0; d4 < 64; ++d4) {
                    float4 c4 = crow[d4];
                    a0 = fma((double)c4.x, (double)zs[px][d4 * 4 + 0], a0);
                    a1 = fma((double)c4.y, (double)zs[px][d4 * 4 + 1], a1);
                    a2 = fma((double)c4.z, (double)zs[px][d4 * 4 + 2], a2);
                    a3 = fma((double)c4.w, (double)zs[px][d4 * 4 + 3], a3);
                }
                float C32 = (float)((a0 + a1) + (a2 + a3));
                float d32 = __fsub_rn(__fadd_rn(A32[n], B32[k]), __fadd_rn(C32, C32));
                unsigned long long key =
                    ((unsigned long long)__float_as_uint(d32) << 32) | (unsigned)k;
                atomicMin(&cell[n], key);
            }
        }
    }
}

// ---------------------------------------------------------------------------
__global__ __launch_bounds__(256) void finalize_kernel(const int* __restrict__ counter,
                                                       const int* __restrict__ list,
                                                       const unsigned long long* __restrict__ cell,
                                                       float* __restrict__ oidx) {
    int cnt = *counter;
    if (cnt > MAXREF) cnt = MAXREF;
    for (int i = blockIdx.x * 256 + threadIdx.x; i < cnt; i += gridDim.x * 256) {
        int n = list[i];
        oidx[n] = (float)(unsigned)(cell[n] & 0xFFFFFFFFull);
    }
}

// ---------------------------------------------------------------------------
__global__ __launch_bounds__(256) void gather_kernel(const float* __restrict__ cb,
                                                     const float* __restrict__ oidx,
                                                     float* __restrict__ zq) {
    const int tid  = threadIdx.x;
    const int s_nl = tid & 63;
    const int s_dw = tid >> 6;
    const int p0   = blockIdx.x * 64;
    const int b    = p0 >> 10;
    const int hw0  = p0 & 1023;

    int idxn = (int)oidx[p0 + s_nl];
    const float4* crow = reinterpret_cast<const float4*>(cb + (size_t)idxn * D_);
    float* zqb = zq + (size_t)b * (D_ * HW_) + hw0;
    #pragma unroll
    for (int r = 0; r < 16; ++r) {
        int d4 = s_dw * 16 + r;
        float4 c4 = crow[d4];
        int d = d4 * 4;
        zqb[(size_t)(d + 0) * HW_ + s_nl] = c4.x;
        zqb[(size_t)(d + 1) * HW_ + s_nl] = c4.y;
        zqb[(size_t)(d + 2) * HW_ + s_nl] = c4.z;
        zqb[(size_t)(d + 3) * HW_ + s_nl] = c4.w;
    }
}

extern "C" void kernel_launch(void* const* d_in, const int* in_sizes, int n_in,
                              void* d_out, int out_size, void* d_ws, size_t ws_size,
                              hipStream_t stream) {
    const float* z  = (const float*)d_in[0];   // [32,256,32,32] fp32
    const float* cb = (const float*)d_in[1];   // [1024,256] fp32

    float* zq   = (float*)d_out;
    float* oidx = zq + (size_t)N_ * D_;

    char* ws = (char*)d_ws;
    int*    counter = (int*)(ws + 0);
    int*    list    = (int*)(ws + 1024);
    float*  B32     = (float*)(ws + 33792);
    float*  A32     = (float*)(ws + 37888);
    short*  cbAhi   = (short*)(ws + 168960);
    short*  cbAlo   = (short*)(ws + 693248);

    // zq-region scratch (consumed before gather overwrites)
    float*              vref = zq;                                   // N_ floats
    unsigned long long* cell = (unsigned long long*)(zq + N_);       // N_ u64

    prep_kernel<<<261, 256, 0, stream>>>(z, cb, A32, B32, cbAhi, cbAlo, counter);
    vq_screen3<<<N_ / 128, 512, 0, stream>>>(
        z, (const short8v*)cbAhi, (const short8v*)cbAlo, B32,
        oidx, vref, cell, counter, list);
    refine_np3<<<MAXREF / 8, 256, 0, stream>>>(z, cb, A32, B32, vref, counter, list, cell);
    finalize_kernel<<<32, 256, 0, stream>>>(counter, list, cell, oidx);
    gather_kernel<<<N_ / 64, 256, 0, stream>>>(cb, oidx, zq);
}

// Round 10
// 207.258 us; speedup vs baseline: 1.4618x; 1.0202x over previous
//
#include <hip/hip_runtime.h>

#define D_   256
#define HW_  1024
#define N_   32768
#define K_   1024

#define MAXREF  8192
#define QMARGIN 5.0e-5f   // flag margin, s-units (needs >= 3.05e-5 + 2*eps_screen ~ 3.75e-5)
#define RMARGIN 4.0e-5f   // refine qualification vs vref, s-units

typedef __attribute__((ext_vector_type(8))) short short8v;  // 8 bf16 (4 VGPRs)
typedef __attribute__((ext_vector_type(4))) float f32x4;    // MFMA acc

// ws layout (bytes):
//   0       counter (int)
//   1024    list[MAXREF] ints
//   33792   B32[1024] floats
//   37888   A32[32768] floats
//   168960  cbAhi fragments (512 KB)
//   693248  cbAlo fragments (512 KB)
//
// zq-region scratch (consumed by refine/finalize before gather overwrites):
//   vref = zq[0 .. N)            (float)
//   cell = zq[N .. 3N)           (u64, packed (d32bits<<32)|k, atomicMin)

// ---------------------------------------------------------------------------
__device__ __forceinline__ unsigned short f2bf_rne(float f) {
    unsigned u = __float_as_uint(f);
    unsigned r = u + 0x7FFFu + ((u >> 16) & 1u);
    return (unsigned short)(r >> 16);
}
__device__ __forceinline__ float bf2f(unsigned short h) {
    return __uint_as_float(((unsigned)h) << 16);
}

// numpy pairwise fp32 sum of squares over 256 elements (stride in elems).
__device__ __forceinline__ float np_sumsq_256(const float* a, int stride) {
    float blk[2];
    #pragma unroll
    for (int h = 0; h < 2; ++h) {
        const float* p = a + (size_t)h * 128 * stride;
        float r[8];
        #pragma unroll
        for (int j = 0; j < 8; ++j) {
            float v = p[(size_t)j * stride];
            r[j] = __fmul_rn(v, v);
        }
        for (int i = 1; i < 16; ++i) {
            #pragma unroll
            for (int j = 0; j < 8; ++j) {
                float v = p[(size_t)(i * 8 + j) * stride];
                r[j] = __fadd_rn(r[j], __fmul_rn(v, v));
            }
        }
        blk[h] = __fadd_rn(__fadd_rn(__fadd_rn(r[0], r[1]), __fadd_rn(r[2], r[3])),
                           __fadd_rn(__fadd_rn(r[4], r[5]), __fadd_rn(r[6], r[7])));
    }
    return __fadd_rn(blk[0], blk[1]);
}

// ---------------------------------------------------------------------------
// Fused prep: bnorm (blocks 0-3) | anorm (4-131) | cbsplit (132-259) | init (260)
// ---------------------------------------------------------------------------
__global__ __launch_bounds__(256) void prep_kernel(const float* __restrict__ z,
                                                   const float* __restrict__ cb,
                                                   float* __restrict__ A32,
                                                   float* __restrict__ B32,
                                                   short* __restrict__ cbAhi,
                                                   short* __restrict__ cbAlo,
                                                   int* __restrict__ counter) {
    const int blk = blockIdx.x;
    const int tid = threadIdx.x;
    if (blk < 4) {
        int k = blk * 256 + tid;
        B32[k] = np_sumsq_256(cb + (size_t)k * D_, 1);
    } else if (blk < 132) {
        int n  = (blk - 4) * 256 + tid;
        int b  = n >> 10;
        int hw = n & 1023;
        A32[n] = np_sumsq_256(z + (size_t)b * (D_ * HW_) + hw, HW_);
    } else if (blk < 260) {
        // fragment-ordered bf16 hi/lo split of codebook
        int c  = (blk - 132) * 256 + tid;   // 0..32767
        int kf = c >> 9;
        int ds = (c >> 6) & 7;
        int q  = (c >> 4) & 3;
        int r  = c & 15;
        int k  = kf * 16 + r;
        int d0 = ds * 32 + q * 8;
        const float* src = cb + (size_t)k * D_ + d0;
        short8v vh, vl;
        #pragma unroll
        for (int j = 0; j < 8; ++j) {
            float f = src[j];
            unsigned short h = f2bf_rne(f);
            float hf = bf2f(h);
            unsigned short l = f2bf_rne(f - hf);
            vh[j] = (short)h;
            vl[j] = (short)l;
        }
        *reinterpret_cast<short8v*>(cbAhi + (size_t)c * 8) = vh;
        *reinterpret_cast<short8v*>(cbAlo + (size_t)c * 8) = vl;
    } else {
        if (tid == 0) *counter = 0;
    }
}

// ---------------------------------------------------------------------------
// MFMA screening v4: 512 threads (8 waves), 128 px/block, full K.
// Wave w owns px = w*16 + r. Staging ds-loop is UNROLLED so bhf/blf are
// statically indexed -> stay in VGPRs (R9 had them demoted to scratch:
// VGPR_Count=64 proved it; rule: runtime-indexed ext_vector arrays spill).
// ---------------------------------------------------------------------------
__global__ __launch_bounds__(512, 2) void vq_screen4(
        const float* __restrict__ z,
        const short8v* __restrict__ cbAhi,
        const short8v* __restrict__ cbAlo,
        const float* __restrict__ B32,
        float* __restrict__ oidx,
        float* __restrict__ vref,
        unsigned long long* __restrict__ cell,
        int* __restrict__ counter,
        int* __restrict__ list)
{
    __shared__ float zt[128][33];     // 16.9 KB
    __shared__ float halfB[K_];       // 4 KB

    const int tid  = threadIdx.x;
    const int lane = tid & 63;
    const int wave = tid >> 6;        // 0..7
    const int q    = lane >> 4;       // 0..3
    const int r    = lane & 15;

    const int p0  = blockIdx.x * 128;
    const int b   = p0 >> 10;
    const int hw0 = p0 & 1023;

    halfB[tid]       = 0.5f * B32[tid];
    halfB[512 + tid] = 0.5f * B32[512 + tid];

    // ---- shared staging, UNROLLED: frags stay register-resident ----
    short8v bhf[8], blf[8];
    const int spx = tid & 127;
    const int sdq = tid >> 7;         // 0..3
    const int px  = wave * 16 + r;
    #pragma unroll
    for (int ds = 0; ds < 8; ++ds) {
        __syncthreads();
        #pragma unroll
        for (int j = 0; j < 8; ++j) {
            int dd = sdq * 8 + j;
            int d  = ds * 32 + dd;
            zt[spx][dd] = z[(size_t)b * (D_ * HW_) + (size_t)d * HW_ + hw0 + spx];
        }
        __syncthreads();
        short8v vh, vl;
        #pragma unroll
        for (int j = 0; j < 8; ++j) {
            float f = zt[px][q * 8 + j];
            unsigned short h = f2bf_rne(f);
            float hf = bf2f(h);
            unsigned short l = f2bf_rne(f - hf);
            vh[j] = (short)h;
            vl[j] = (short)l;
        }
        bhf[ds] = vh;
        blf[ds] = vl;
    }
    __syncthreads();

    // ---- k-loop: 2 independent acc chains, a-frags L1-broadcast ----
    float v1 = 3.4e38f, v2v = 3.4e38f;
    int   k1 = 0;

    for (int ch = 0; ch < 32; ++ch) {
        f32x4 acc0 = {0.f,0.f,0.f,0.f};
        f32x4 acc1 = {0.f,0.f,0.f,0.f};

        #pragma unroll
        for (int ds = 0; ds < 8; ++ds) {
            int base0 = ((ch * 2 + 0) * 8 + ds) * 64 + lane;
            int base1 = ((ch * 2 + 1) * 8 + ds) * 64 + lane;
            short8v a0h = cbAhi[base0], a0l = cbAlo[base0];
            short8v a1h = cbAhi[base1], a1l = cbAlo[base1];

            acc0 = __builtin_amdgcn_mfma_f32_16x16x32_bf16(a0h, bhf[ds], acc0, 0,0,0);
            acc1 = __builtin_amdgcn_mfma_f32_16x16x32_bf16(a1h, bhf[ds], acc1, 0,0,0);
            acc0 = __builtin_amdgcn_mfma_f32_16x16x32_bf16(a0l, bhf[ds], acc0, 0,0,0);
            acc1 = __builtin_amdgcn_mfma_f32_16x16x32_bf16(a1l, bhf[ds], acc1, 0,0,0);
            acc0 = __builtin_amdgcn_mfma_f32_16x16x32_bf16(a0h, blf[ds], acc0, 0,0,0);
            acc1 = __builtin_amdgcn_mfma_f32_16x16x32_bf16(a1h, blf[ds], acc1, 0,0,0);
        }

        // extraction: D row = q*4+reg (code), col = r (pixel)
        #pragma unroll
        for (int kf = 0; kf < 2; ++kf) {
            int kbase = ch * 32 + kf * 16 + q * 4;
            #pragma unroll
            for (int reg = 0; reg < 4; ++reg) {
                float s = halfB[kbase + reg] - ((kf == 0) ? acc0[reg] : acc1[reg]);
                int  kk = kbase + reg;
                bool lt = s < v1;
                v2v = lt ? v1 : fminf(v2v, s);
                k1  = lt ? kk : k1;
                v1  = lt ? s  : v1;
            }
        }
        __builtin_amdgcn_s_barrier();   // keep waves chunk-aligned for L1 reuse
    }

    // ---- merge the 4 q-groups per pixel (lanes l, l^16, l^32, l^48) ----
    float a1 = v1, a2 = v2v;
    int   ak = k1;
    #pragma unroll
    for (int off = 16; off <= 32; off <<= 1) {
        float o1 = __shfl_xor(a1, off, 64);
        float o2 = __shfl_xor(a2, off, 64);
        int   ok = __shfl_xor(ak, off, 64);
        if (o1 < a1 || (o1 == a1 && ok < ak)) {
            a2 = fminf(a1, o2); a1 = o1; ak = ok;
        } else {
            a2 = fminf(a2, o1);
        }
    }
    if (q == 0) {
        int n = p0 + wave * 16 + r;
        oidx[n] = (float)ak;
        vref[n] = a1;
        if (a2 - a1 < QMARGIN) {
            int slot = atomicAdd(counter, 1);
            if (slot < MAXREF) {
                list[slot] = n;
                cell[n] = 0xFFFFFFFFFFFFFFFFull;
            }
        }
    }
}

// ---------------------------------------------------------------------------
// Refinement v3: 8 flagged px/block; zs read via float4 once per (px,d4),
// reused over the thread's 4 codes. Qualifying (px,k): np-emulated d32 +
// atomicMin packed (d32,k) -> lexicographic = numpy first-occurrence argmin.
// ---------------------------------------------------------------------------
__global__ __launch_bounds__(256) void refine_np3(const float* __restrict__ z,
                                                  const float* __restrict__ cb,
                                                  const float* __restrict__ A32,
                                                  const float* __restrict__ B32,
                                                  const float* __restrict__ vref,
                                                  const int* __restrict__ counter,
                                                  const int* __restrict__ list,
                                                  unsigned long long* __restrict__ cell) {
    __shared__ float zs[8][260];
    __shared__ int   pid[8];
    __shared__ float pvref[8];

    const int tid = threadIdx.x;
    int cnt = *counter;
    if (cnt > MAXREF) cnt = MAXREF;
    int i0 = blockIdx.x * 8;
    if (i0 >= cnt) return;

    if (tid < 8) {
        int idx   = i0 + tid;
        int valid = idx < cnt;
        int n     = list[valid ? idx : i0];
        pid[tid]   = n;
        pvref[tid] = valid ? vref[n] : -1e30f;   // invalid slot: never qualifies
    }
    __syncthreads();

    {   // stage z rows (8 px x 256 d)
        int px = tid >> 5;
        int dl = tid & 31;
        int n  = pid[px];
        int bb = n >> 10, hw = n & 1023;
        const float* zb = z + (size_t)bb * (D_ * HW_) + hw;
        #pragma unroll
        for (int j = 0; j < 8; ++j) {
            int d = dl * 8 + j;
            zs[px][d] = zb[(size_t)d * HW_];
        }
    }
    __syncthreads();

    const int kb = tid * 4;
    float a[4][8];
    #pragma unroll
    for (int jj = 0; jj < 4; ++jj)
        #pragma unroll
        for (int px = 0; px < 8; ++px) a[jj][px] = 0.f;

    for (int d4 = 0; d4 < 64; ++d4) {
        float4 c[4];
        #pragma unroll
        for (int jj = 0; jj < 4; ++jj)
            c[jj] = *reinterpret_cast<const float4*>(cb + (size_t)(kb + jj) * D_ + d4 * 4);
        #pragma unroll
        for (int px = 0; px < 8; ++px) {
            float4 z4 = *reinterpret_cast<const float4*>(&zs[px][d4 * 4]);
            #pragma unroll
            for (int jj = 0; jj < 4; ++jj) {
                a[jj][px] = fmaf(c[jj].x, z4.x, a[jj][px]);
                a[jj][px] = fmaf(c[jj].y, z4.y, a[jj][px]);
                a[jj][px] = fmaf(c[jj].z, z4.z, a[jj][px]);
                a[jj][px] = fmaf(c[jj].w, z4.w, a[jj][px]);
            }
        }
    }

    #pragma unroll
    for (int jj = 0; jj < 4; ++jj) {
        int k = kb + jj;
        float hb = 0.5f * B32[k];
        #pragma unroll
        for (int px = 0; px < 8; ++px) {
            float s = hb - a[jj][px];
            if (s - pvref[px] < RMARGIN) {
                int n = pid[px];
                const float4* crow = reinterpret_cast<const float4*>(cb + (size_t)k * D_);
                double a0 = 0.0, a1 = 0.0, a2 = 0.0, a3 = 0.0;
                for (int d4 = 0; d4 < 64; ++d4) {
                    float4 c4 = crow[d4];
                    a0 = fma((double)c4.x, (double)zs[px][d4 * 4 + 0], a0);
                    a1 = fma((double)c4.y, (double)zs[px][d4 * 4 + 1], a1);
                    a2 = fma((double)c4.z, (double)zs[px][d4 * 4 + 2], a2);
                    a3 = fma((double)c4.w, (double)zs[px][d4 * 4 + 3], a3);
                }
                float C32 = (float)((a0 + a1) + (a2 + a3));
                float d32 = __fsub_rn(__fadd_rn(A32[n], B32[k]), __fadd_rn(C32, C32));
                unsigned long long key =
                    ((unsigned long long)__float_as_uint(d32) << 32) | (unsigned)k;
                atomicMin(&cell[n], key);
            }
        }
    }
}

// ---------------------------------------------------------------------------
__global__ __launch_bounds__(256) void finalize_kernel(const int* __restrict__ counter,
                                                       const int* __restrict__ list,
                                                       const unsigned long long* __restrict__ cell,
                                                       float* __restrict__ oidx) {
    int cnt = *counter;
    if (cnt > MAXREF) cnt = MAXREF;
    for (int i = blockIdx.x * 256 + threadIdx.x; i < cnt; i += gridDim.x * 256) {
        int n = list[i];
        oidx[n] = (float)(unsigned)(cell[n] & 0xFFFFFFFFull);
    }
}

// ---------------------------------------------------------------------------
__global__ __launch_bounds__(256) void gather_kernel(const float* __restrict__ cb,
                                                     const float* __restrict__ oidx,
                                                     float* __restrict__ zq) {
    const int tid  = threadIdx.x;
    const int s_nl = tid & 63;
    const int s_dw = tid >> 6;
    const int p0   = blockIdx.x * 64;
    const int b    = p0 >> 10;
    const int hw0  = p0 & 1023;

    int idxn = (int)oidx[p0 + s_nl];
    const float4* crow = reinterpret_cast<const float4*>(cb + (size_t)idxn * D_);
    float* zqb = zq + (size_t)b * (D_ * HW_) + hw0;
    #pragma unroll
    for (int r = 0; r < 16; ++r) {
        int d4 = s_dw * 16 + r;
        float4 c4 = crow[d4];
        int d = d4 * 4;
        zqb[(size_t)(d + 0) * HW_ + s_nl] = c4.x;
        zqb[(size_t)(d + 1) * HW_ + s_nl] = c4.y;
        zqb[(size_t)(d + 2) * HW_ + s_nl] = c4.z;
        zqb[(size_t)(d + 3) * HW_ + s_nl] = c4.w;
    }
}

extern "C" void kernel_launch(void* const* d_in, const int* in_sizes, int n_in,
                              void* d_out, int out_size, void* d_ws, size_t ws_size,
                              hipStream_t stream) {
    const float* z  = (const float*)d_in[0];   // [32,256,32,32] fp32
    const float* cb = (const float*)d_in[1];   // [1024,256] fp32

    float* zq   = (float*)d_out;
    float* oidx = zq + (size_t)N_ * D_;

    char* ws = (char*)d_ws;
    int*    counter = (int*)(ws + 0);
    int*    list    = (int*)(ws + 1024);
    float*  B32     = (float*)(ws + 33792);
    float*  A32     = (float*)(ws + 37888);
    short*  cbAhi   = (short*)(ws + 168960);
    short*  cbAlo   = (short*)(ws + 693248);

    // zq-region scratch (consumed before gather overwrites)
    float*              vref = zq;                                   // N_ floats
    unsigned long long* cell = (unsigned long long*)(zq + N_);       // N_ u64

    prep_kernel<<<261, 256, 0, stream>>>(z, cb, A32, B32, cbAhi, cbAlo, counter);
    vq_screen4<<<N_ / 128, 512, 0, stream>>>(
        z, (const short8v*)cbAhi, (const short8v*)cbAlo, B32,
        oidx, vref, cell, counter, list);
    refine_np3<<<MAXREF / 8, 256, 0, stream>>>(z, cb, A32, B32, vref, counter, list, cell);
    finalize_kernel<<<32, 256, 0, stream>>>(counter, list, cell, oidx);
    gather_kernel<<<N_ / 64, 256, 0, stream>>>(cb, oidx, zq);
}